// Round 9
// baseline (3600.792 us; speedup 1.0000x reference)
//
#include <hip/hip_runtime.h>

typedef unsigned short ushort_t;
typedef unsigned int uint_t;
typedef unsigned long long ull_t;
typedef __attribute__((ext_vector_type(8))) short short8;
typedef __attribute__((ext_vector_type(4))) float f32x4;

#define MFMA16(a, b, c) __builtin_amdgcn_mfma_f32_16x16x32_bf16((a), (b), (c), 0, 0, 0)

__device__ __forceinline__ ushort_t f2bf(float f) {
  union { float f; uint_t u; } v; v.f = f;
  uint_t r = v.u + 0x7fffu + ((v.u >> 16) & 1u);
  return (ushort_t)(r >> 16);
}
__device__ __forceinline__ float sigm(float x) { return 1.f / (1.f + __expf(-x)); }

// Device-coherent 16B load (two 8B relaxed agent atomics). RING fallback only.
__device__ __forceinline__ short8 ldc(const ushort_t* p) {
  union { ull_t q[2]; short8 v; } u;
  u.q[0] = __hip_atomic_load((const ull_t*)p, __ATOMIC_RELAXED, __HIP_MEMORY_SCOPE_AGENT);
  u.q[1] = __hip_atomic_load((const ull_t*)(p + 4), __ATOMIC_RELAXED, __HIP_MEMORY_SCOPE_AGENT);
  return u.v;
}
template <bool SEQ>
__device__ __forceinline__ short8 ldh(const ushort_t* p) {
  if constexpr (SEQ) return *(const short8*)p;  // fresh (never-reused) address: cached load is coherent
  else return ldc(p);
}
// Write-through stores land at the device coherence point.
__device__ __forceinline__ void stc8(ushort_t* p, ull_t v) {
  __hip_atomic_store((ull_t*)p, v, __ATOMIC_RELAXED, __HIP_MEMORY_SCOPE_AGENT);
}
__device__ __forceinline__ void stc4(uint_t* p, uint_t v) {
  __hip_atomic_store(p, v, __ATOMIC_RELAXED, __HIP_MEMORY_SCOPE_AGENT);
}

// light barrier: drains LDS ops only; global stores stay in flight
__device__ __forceinline__ void barrier_l() {
  asm volatile("s_waitcnt lgkmcnt(0)" ::: "memory");
  __builtin_amdgcn_s_barrier();
  asm volatile("" ::: "memory");
}

__device__ __forceinline__ size_t hidx(int ko, int b0, int l15) {
  return (size_t)((ko >> 4) * 256 + b0 + l15) * 16 + (ko & 15);
}

// ---------------- workspace layout (bytes) ----------------
#define OFF_XBF  0UL            // bf16 x^T [256 t][256 b][128]  16777216
#define OFF_W1T  16777216UL     // bf16 W1^T [1536][128]   393216
#define OFF_R1T  17170432UL     // bf16 R1^T [1536][512]   1572864
#define OFF_W2T  18743296UL     // bf16 W2^T [1536][512]   1572864
#define OFF_R2T  20316160UL     // bf16 R2^T [1536][512]   1572864
#define OFF_W3T  21889024UL     // bf16 W3^T [192][512]    196608
#define OFF_R3T  22085632UL     // bf16 R3^T [192][64]     24576
#define OFF_CNT  22110208UL     // uint flags[8 grp][32 w]
#define OFF_H    22114304UL
#define H1_BYTES_SEQ  (257UL * 262144UL)
#define H3_BYTES_SEQ  (257UL * 32768UL)
#define SEQ_NEED (OFF_H + 2UL * H1_BYTES_SEQ + H3_BYTES_SEQ)
#define H1_BYTES_RING (4UL * 262144UL)

// ---------------- init kernels ----------------
__global__ void k_cvtx(const float* __restrict__ x, ushort_t* __restrict__ xb) {
  const int i = blockIdx.x * 256 + threadIdx.x;
  const int d4 = i & 31;
  const int t = (i >> 5) & 255;
  const int b = i >> 13;
  const float4 v = ((const float4*)x)[i];
  ushort4 o;
  o.x = f2bf(v.x); o.y = f2bf(v.y); o.z = f2bf(v.z); o.w = f2bf(v.w);
  ((ushort4*)xb)[(((t << 8) + b) << 5) + d4] = o;
}

__global__ void k_tr(const float* __restrict__ src, ushort_t* __restrict__ dst,
                     int K, int G, int n) {
  const int i = blockIdx.x * 256 + threadIdx.x;
  if (i >= n) return;
  const int g = i / K, k = i - g * K;
  dst[i] = f2bf(src[(size_t)k * G + g]);
}

__global__ void k_zero(uint_t* h1, uint_t* h2, uint_t* h3, uint_t* cnt) {
  const int i = blockIdx.x * 256 + threadIdx.x;
  if (i < 65536) h1[i] = 0;                    // h1 slot 0 (h1[-1]=0)
  else if (i < 131072) h2[i - 65536] = 0;      // h2 slot 0
  else if (i < 139264) h3[i - 131072] = 0;     // h3 slot 0
  else if (i < 139776) cnt[i - 139264] = 0;
}

// ---------------- persistent pipelined GRU ----------------
// R5 structure + protocol VERBATIM (the verified 2385us kernel): W2 in LDS,
// chain-split epilogues, flag-array barrier, agent/MALL coherence. The R7/R8
// chain-split redesign failed verification and is abandoned. Two safe deltas:
// (1) REFILL REORDER on the straggler isC lay0 waves: the B-chain L3 refill
//     burst is issued, then the INDEPENDENT B-chain L1 MFMAs run (hiding the
//     ~900cy MALL latency), then the B-L3 MFMAs consume the refill. Pure
//     same-wave reordering, no semantic change.
// (2) Phase-2 barriers are now conditional on isC (WG-uniform branch, so
//     s_barrier participation stays WG-consistent): non-isC WGs skip 2 of 4
//     per-step barriers.
template <bool SEQ>
__global__ __launch_bounds__(256, 1)
void gru_main(const ushort_t* __restrict__ xbf,
              const ushort_t* __restrict__ W1t, const ushort_t* __restrict__ R1t,
              const ushort_t* __restrict__ W2t, const ushort_t* __restrict__ R2t,
              const ushort_t* __restrict__ W3t, const ushort_t* __restrict__ R3t,
              const float* __restrict__ b1, const float* __restrict__ b2,
              const float* __restrict__ b3,
              ushort_t* __restrict__ h1s, ushort_t* __restrict__ h2s,
              ushort_t* __restrict__ h3s,
              uint_t* __restrict__ cnt, float* __restrict__ out) {
  __shared__ char ldsb[64512] __attribute__((aligned(16)));
  char* w2b = ldsb + 15360;            // 49152 B swizzled W2
#define RGN(r) (*(f32x4*)(ldsb + ((r) << 10) + ((size_t)lane << 4)))
  const int tid = threadIdx.x, bid = blockIdx.x;
  const int grp = bid & 7;
  const int w = bid >> 3;               // 0..31: u-col group
  const int b0A = grp << 5, b0B = b0A + 16;
  const int lane = tid & 63, wid = tid >> 6;
  const int l15 = lane & 15, quad = lane >> 4, q8 = quad << 3;
  const int lay = wid >> 1, sub = wid & 1;
  const bool isC = (w >= 28);
  const int u = (w << 4) + l15;
  const int u3 = ((w - 28) << 4) + l15;

  // ---- W2 -> LDS (swizzled), by lay1 waves ----
  if (lay == 1) {
#pragma unroll
    for (int g = 0; g < 3; ++g)
#pragma unroll
      for (int kk = 0; kk < 8; ++kk) {
        const int k2 = sub * 8 + kk;
        const short8 v = *(const short8*)&W2t[(size_t)(g * 512 + u) * 512 + k2 * 32 + q8];
        const int off = ((((g * 16 + l15) << 10) + ((k2 * 32 + q8) << 1)) ^ ((l15 & 7) << 4));
        *(short8*)(w2b + off) = v;
      }
  }

  // ---- register-resident weights ----
  short8 wreg[33];
  if (lay == 0) {
    if (sub == 0) {
#pragma unroll
      for (int g = 0; g < 3; ++g) {
#pragma unroll
        for (int kk = 0; kk < 4; ++kk)
          wreg[g * 4 + kk] = *(const short8*)&W1t[(size_t)(g * 512 + u) * 128 + kk * 32 + q8];
#pragma unroll
        for (int kk = 0; kk < 5; ++kk)
          wreg[12 + g * 5 + kk] = *(const short8*)&R1t[(size_t)(g * 512 + u) * 512 + kk * 32 + q8];
      }
    } else {
#pragma unroll
      for (int g = 0; g < 3; ++g)
#pragma unroll
        for (int kk = 0; kk < 11; ++kk)
          wreg[g * 11 + kk] = *(const short8*)&R1t[(size_t)(g * 512 + u) * 512 + (5 + kk) * 32 + q8];
    }
  } else {
#pragma unroll
    for (int g = 0; g < 3; ++g)
#pragma unroll
      for (int kk = 0; kk < 8; ++kk)
        wreg[g * 8 + kk] = *(const short8*)&R2t[(size_t)(g * 512 + u) * 512 + (sub * 8 + kk) * 32 + q8];
  }
  __syncthreads();   // W2 LDS ready

  // ---- biases ----
  const float bzs1 = b1[u] + b1[1536 + u];
  const float brs1 = b1[512 + u] + b1[2048 + u];
  const float bh10 = b1[1024 + u], bh11 = b1[2560 + u];
  const float bzs2 = b2[u] + b2[1536 + u];
  const float brs2 = b2[512 + u] + b2[2048 + u];
  const float bh20 = b2[1024 + u], bh21 = b2[2560 + u];
  float czs = 0, crs = 0, ch0 = 0, ch1 = 0;
  if (isC) {
    czs = b3[u3] + b3[192 + u3];
    crs = b3[64 + u3] + b3[256 + u3];
    ch0 = b3[128 + u3]; ch1 = b3[320 + u3];
  }

  // per-wave persistent state: this wave's epilogue chain
  float h1st[4] = {0, 0, 0, 0};
  float h2st[4] = {0, 0, 0, 0};
  float h3st[4] = {0, 0, 0, 0};
  const f32x4 z4 = {0.f, 0.f, 0.f, 0.f};
  uint_t* flags = cnt;

#pragma unroll 1
  for (int s = 0; s < 258; ++s) {
    // ---- spin: all 32 WGs of the group done with superstep s-1 ----
    {
      const uint_t* fl = flags + grp * 32 + (lane & 31);
      while (true) {
        const uint_t v = __hip_atomic_load(fl, __ATOMIC_RELAXED, __HIP_MEMORY_SCOPE_AGENT);
        if (__all((int)(v >= (uint_t)s))) break;
        __builtin_amdgcn_s_sleep(1);
      }
      asm volatile("" ::: "memory");   // no load hoisting above the spin
    }
    // slot(t) = t+1 (slot 0 = zeros); ush offsets
    const size_t sl_h1rd = (size_t)(SEQ ? s : (s & 3)) * 131072;             // h1[s-1]
    const size_t sl_h1wr = (size_t)(SEQ ? (s + 1) : ((s + 1) & 3)) * 131072;
    const size_t sl_h2rd = (size_t)(SEQ ? (s - 1) : ((s - 1) & 3)) * 131072; // h2[s-2]
    const size_t sl_h2wr = (size_t)(SEQ ? s : (s & 3)) * 131072;             // h2[s-1]
    const size_t sl_h3rd = (size_t)(SEQ ? (s - 2) : ((s - 2) & 3)) * 16384;  // h3[s-3]
    const size_t sl_h3wr = (size_t)(SEQ ? (s - 1) : ((s - 1) & 3)) * 16384;  // h3[s-2]

    f32x4 azA = z4, arrA = z4, ahxA = z4, ahrA = z4;
    f32x4 azB = z4, arrB = z4, ahxB = z4, ahrB = z4;
    f32x4 dzA = z4, drrA = z4, dhxA = z4, dhrA = z4;
    f32x4 dzB = z4, drrB = z4, dhxB = z4, dhrB = z4;

    if (lay == 0) {
      const ushort_t* h1rd = h1s + sl_h1rd;
      const ushort_t* h2rd = h2s + sl_h2rd;
      if (sub == 0) {
        // ------- lay0-sub0: W1 + R1 k[0,160); isC: W3 k[0,256) + R3 -------
        short8 sx[4], sh[5], s2A[8], s3[2];
        // ISSUE burst: chain A (+ L3 A-side)
        if (s < 256) {
          const ushort_t* xrA = xbf + ((size_t)s * 256 + b0A + l15) * 128;
#pragma unroll
          for (int kk = 0; kk < 4; ++kk) sx[kk] = *(const short8*)&xrA[kk * 32 + q8];
#pragma unroll
          for (int kk = 0; kk < 5; ++kk)
            sh[kk] = ldh<SEQ>(&h1rd[hidx(kk * 32 + q8, b0A, l15)]);
        }
        if (isC && s >= 2) {
          const ushort_t* h3rd = h3s + sl_h3rd;
#pragma unroll
          for (int kk = 0; kk < 8; ++kk)
            s2A[kk] = ldh<SEQ>(&h2rd[hidx(kk * 32 + q8, b0A, l15)]);
#pragma unroll
          for (int kk = 0; kk < 2; ++kk)
            s3[kk] = ldh<SEQ>(&h3rd[hidx(kk * 32 + q8, b0A, l15)]);
        }
        if (s < 256) {
          // A MFMAs
#pragma unroll
          for (int kk = 0; kk < 4; ++kk) {
            azA  = MFMA16(sx[kk], wreg[kk], azA);
            arrA = MFMA16(sx[kk], wreg[4 + kk], arrA);
            ahxA = MFMA16(sx[kk], wreg[8 + kk], ahxA);
          }
#pragma unroll
          for (int kk = 0; kk < 5; ++kk) {
            azA  = MFMA16(sh[kk], wreg[12 + kk], azA);
            arrA = MFMA16(sh[kk], wreg[17 + kk], arrA);
            ahrA = MFMA16(sh[kk], wreg[22 + kk], ahrA);
          }
          // refill with chain B (register reuse), one burst
          const ushort_t* xrB = xbf + ((size_t)s * 256 + b0B + l15) * 128;
#pragma unroll
          for (int kk = 0; kk < 4; ++kk) sx[kk] = *(const short8*)&xrB[kk * 32 + q8];
#pragma unroll
          for (int kk = 0; kk < 5; ++kk)
            sh[kk] = ldh<SEQ>(&h1rd[hidx(kk * 32 + q8, b0B, l15)]);
        }
        if (isC && s >= 2) {
          const ushort_t* h3rd = h3s + sl_h3rd;
          // A: h2 @ W3 k[0,256)
#pragma unroll
          for (int kk = 0; kk < 8; ++kk) {
            const int ko = kk * 32 + q8;
            dzA  = MFMA16(s2A[kk], *(const short8*)&W3t[(size_t)u3 * 512 + ko], dzA);
            drrA = MFMA16(s2A[kk], *(const short8*)&W3t[(size_t)(64 + u3) * 512 + ko], drrA);
            dhxA = MFMA16(s2A[kk], *(const short8*)&W3t[(size_t)(128 + u3) * 512 + ko], dhxA);
          }
          // A: h3 @ R3
#pragma unroll
          for (int kk = 0; kk < 2; ++kk) {
            const int ko = kk * 32 + q8;
            dzA  = MFMA16(s3[kk], *(const short8*)&R3t[(size_t)u3 * 64 + ko], dzA);
            drrA = MFMA16(s3[kk], *(const short8*)&R3t[(size_t)(64 + u3) * 64 + ko], drrA);
            dhrA = MFMA16(s3[kk], *(const short8*)&R3t[(size_t)(128 + u3) * 64 + ko], dhrA);
          }
          // ISSUE refill: B-side h2 + h3 (latency hidden by B L1 MFMAs below)
#pragma unroll
          for (int kk = 0; kk < 8; ++kk)
            s2A[kk] = ldh<SEQ>(&h2rd[hidx(kk * 32 + q8, b0B, l15)]);
#pragma unroll
          for (int kk = 0; kk < 2; ++kk)
            s3[kk] = ldh<SEQ>(&h3rd[hidx(kk * 32 + q8, b0B, l15)]);
        }
        if (s < 256) {
          // B L1 MFMAs (independent of the L3 refill -> hides its latency)
#pragma unroll
          for (int kk = 0; kk < 4; ++kk) {
            azB  = MFMA16(sx[kk], wreg[kk], azB);
            arrB = MFMA16(sx[kk], wreg[4 + kk], arrB);
            ahxB = MFMA16(sx[kk], wreg[8 + kk], ahxB);
          }
#pragma unroll
          for (int kk = 0; kk < 5; ++kk) {
            azB  = MFMA16(sh[kk], wreg[12 + kk], azB);
            arrB = MFMA16(sh[kk], wreg[17 + kk], arrB);
            ahrB = MFMA16(sh[kk], wreg[22 + kk], ahrB);
          }
        }
        if (isC && s >= 2) {
          // B L3 MFMAs (refill has drained under the B L1 block)
#pragma unroll
          for (int kk = 0; kk < 8; ++kk) {
            const int ko = kk * 32 + q8;
            dzB  = MFMA16(s2A[kk], *(const short8*)&W3t[(size_t)u3 * 512 + ko], dzB);
            drrB = MFMA16(s2A[kk], *(const short8*)&W3t[(size_t)(64 + u3) * 512 + ko], drrB);
            dhxB = MFMA16(s2A[kk], *(const short8*)&W3t[(size_t)(128 + u3) * 512 + ko], dhxB);
          }
#pragma unroll
          for (int kk = 0; kk < 2; ++kk) {
            const int ko = kk * 32 + q8;
            dzB  = MFMA16(s3[kk], *(const short8*)&R3t[(size_t)u3 * 64 + ko], dzB);
            drrB = MFMA16(s3[kk], *(const short8*)&R3t[(size_t)(64 + u3) * 64 + ko], drrB);
            dhrB = MFMA16(s3[kk], *(const short8*)&R3t[(size_t)(128 + u3) * 64 + ko], dhrB);
          }
        }
      } else {
        // ------- lay0-sub1: R1 k[160,512); isC: W3 k[256,512) -------
        short8 sh[11], s2A[8];
        if (s < 256) {
#pragma unroll
          for (int kk = 0; kk < 11; ++kk)
            sh[kk] = ldh<SEQ>(&h1rd[hidx((5 + kk) * 32 + q8, b0A, l15)]);
        }
        if (isC && s >= 2) {
#pragma unroll
          for (int kk = 0; kk < 8; ++kk)
            s2A[kk] = ldh<SEQ>(&h2rd[hidx((8 + kk) * 32 + q8, b0A, l15)]);
        }
        if (s < 256) {
#pragma unroll
          for (int kk = 0; kk < 11; ++kk) {
            azA  = MFMA16(sh[kk], wreg[kk], azA);
            arrA = MFMA16(sh[kk], wreg[11 + kk], arrA);
            ahrA = MFMA16(sh[kk], wreg[22 + kk], ahrA);
          }
          // refill with chain B (one burst)
#pragma unroll
          for (int kk = 0; kk < 11; ++kk)
            sh[kk] = ldh<SEQ>(&h1rd[hidx((5 + kk) * 32 + q8, b0B, l15)]);
        }
        if (isC && s >= 2) {
          // A W3 MFMAs (hide the sh(B) refill above)
#pragma unroll
          for (int kk = 0; kk < 8; ++kk) {
            const int ko = (8 + kk) * 32 + q8;
            dzA  = MFMA16(s2A[kk], *(const short8*)&W3t[(size_t)u3 * 512 + ko], dzA);
            drrA = MFMA16(s2A[kk], *(const short8*)&W3t[(size_t)(64 + u3) * 512 + ko], drrA);
            dhxA = MFMA16(s2A[kk], *(const short8*)&W3t[(size_t)(128 + u3) * 512 + ko], dhxA);
          }
          // ISSUE refill: B-side h2 (latency hidden by B L1 MFMAs below)
#pragma unroll
          for (int kk = 0; kk < 8; ++kk)
            s2A[kk] = ldh<SEQ>(&h2rd[hidx((8 + kk) * 32 + q8, b0B, l15)]);
        }
        if (s < 256) {
          // B L1 MFMAs (independent of the L3 refill)
#pragma unroll
          for (int kk = 0; kk < 11; ++kk) {
            azB  = MFMA16(sh[kk], wreg[kk], azB);
            arrB = MFMA16(sh[kk], wreg[11 + kk], arrB);
            ahrB = MFMA16(sh[kk], wreg[22 + kk], ahrB);
          }
        }
        if (isC && s >= 2) {
          // B W3 MFMAs
#pragma unroll
          for (int kk = 0; kk < 8; ++kk) {
            const int ko = (8 + kk) * 32 + q8;
            dzB  = MFMA16(s2A[kk], *(const short8*)&W3t[(size_t)u3 * 512 + ko], dzB);
            drrB = MFMA16(s2A[kk], *(const short8*)&W3t[(size_t)(64 + u3) * 512 + ko], drrB);
            dhxB = MFMA16(s2A[kk], *(const short8*)&W3t[(size_t)(128 + u3) * 512 + ko], dhxB);
          }
        }
      }
    } else {
      // ------- lay1: W2 (LDS) + R2 (regs), K-half [sub*256, sub*256+256) -------
      if (s >= 1 && s < 257) {
        const ushort_t* h1rd = h1s + sl_h1rd;
        const ushort_t* h2rd = h2s + sl_h2rd;
        short8 sa[8], sb[8];
#pragma unroll
        for (int kk = 0; kk < 8; ++kk) {
          const size_t ao = hidx((sub * 8 + kk) * 32 + q8, b0A, l15);
          sa[kk] = ldh<SEQ>(&h1rd[ao]);
          sb[kk] = ldh<SEQ>(&h2rd[ao]);
        }
#pragma unroll
        for (int kk = 0; kk < 8; ++kk) {
          const int ko = (sub * 8 + kk) * 32 + q8;
          const int o0 = ((((0 * 16 + l15) << 10) + (ko << 1)) ^ ((l15 & 7) << 4));
          const int o1 = ((((1 * 16 + l15) << 10) + (ko << 1)) ^ ((l15 & 7) << 4));
          const int o2 = ((((2 * 16 + l15) << 10) + (ko << 1)) ^ ((l15 & 7) << 4));
          azA  = MFMA16(sa[kk], *(const short8*)(w2b + o0), azA);
          arrA = MFMA16(sa[kk], *(const short8*)(w2b + o1), arrA);
          ahxA = MFMA16(sa[kk], *(const short8*)(w2b + o2), ahxA);
          azA  = MFMA16(sb[kk], wreg[kk], azA);
          arrA = MFMA16(sb[kk], wreg[8 + kk], arrA);
          ahrA = MFMA16(sb[kk], wreg[16 + kk], ahrA);
        }
        // refill with chain B (register reuse)
#pragma unroll
        for (int kk = 0; kk < 8; ++kk) {
          const size_t ao = hidx((sub * 8 + kk) * 32 + q8, b0B, l15);
          sa[kk] = ldh<SEQ>(&h1rd[ao]);
          sb[kk] = ldh<SEQ>(&h2rd[ao]);
        }
#pragma unroll
        for (int kk = 0; kk < 8; ++kk) {
          const int ko = (sub * 8 + kk) * 32 + q8;
          const int o0 = ((((0 * 16 + l15) << 10) + (ko << 1)) ^ ((l15 & 7) << 4));
          const int o1 = ((((1 * 16 + l15) << 10) + (ko << 1)) ^ ((l15 & 7) << 4));
          const int o2 = ((((2 * 16 + l15) << 10) + (ko << 1)) ^ ((l15 & 7) << 4));
          azB  = MFMA16(sa[kk], *(const short8*)(w2b + o0), azB);
          arrB = MFMA16(sa[kk], *(const short8*)(w2b + o1), arrB);
          ahxB = MFMA16(sa[kk], *(const short8*)(w2b + o2), ahxB);
          azB  = MFMA16(sb[kk], wreg[kk], azB);
          arrB = MFMA16(sb[kk], wreg[8 + kk], arrB);
          ahrB = MFMA16(sb[kk], wreg[16 + kk], ahrB);
        }
      }
    }

    // ---- phase 1: partner-chain partial writes ----
    if (lay == 0) {
      if (sub == 1) {
        if (s < 256) { RGN(0) = azA; RGN(1) = arrA; RGN(2) = ahrA; }
      } else {
        if (s < 256) { RGN(3) = azB; RGN(4) = arrB; RGN(5) = ahxB; RGN(6) = ahrB; }
      }
    } else {
      if (s >= 1 && s < 257) {
        if (sub == 1) { RGN(7) = azA; RGN(8) = arrA; RGN(9) = ahxA; RGN(10) = ahrA; }
        else          { RGN(11) = azB; RGN(12) = arrB; RGN(13) = ahxB; RGN(14) = ahrB; }
      }
    }
    barrier_l();

    // ---- L1/L2 epilogues (sub0 -> chain A, sub1 -> chain B) ----
    if (lay == 0) {
      if (sub == 0) {
        if (s < 256) {
          const f32x4 ez = RGN(0), er = RGN(1), ehr = RGN(2);
          ushort_t* stg = (ushort_t*)ldsb;
#pragma unroll
          for (int r = 0; r < 4; ++r) {
            const float z = sigm(azA[r] + ez[r] + bzs1);
            const float rg = sigm(arrA[r] + er[r] + brs1);
            const float hh = fmaxf(ahxA[r] + bh10 + rg * (ahrA[r] + ehr[r] + bh11), 0.f);
            const float hn = z * h1st[r] + (1.f - z) * hh;
            h1st[r] = hn;
            stg[(quad * 4 + r) * 16 + l15] = f2bf(hn);
          }
          asm volatile("s_waitcnt lgkmcnt(0)" ::: "memory");
          stc8(&h1s[sl_h1wr + (size_t)w * 4096 + (size_t)b0A * 16 + lane * 4],
               *(const ull_t*)&stg[lane * 4]);
        }
      } else {
        if (s < 256) {
          const f32x4 ez = RGN(3), er = RGN(4), ehx = RGN(5), ehr = RGN(6);
          ushort_t* stg = (ushort_t*)(ldsb + 3072);
#pragma unroll
          for (int r = 0; r < 4; ++r) {
            const float z = sigm(azB[r] + ez[r] + bzs1);
            const float rg = sigm(arrB[r] + er[r] + brs1);
            const float hh = fmaxf(ehx[r] + bh10 + rg * (ahrB[r] + ehr[r] + bh11), 0.f);
            const float hn = z * h1st[r] + (1.f - z) * hh;
            h1st[r] = hn;
            stg[(quad * 4 + r) * 16 + l15] = f2bf(hn);
          }
          asm volatile("s_waitcnt lgkmcnt(0)" ::: "memory");
          stc8(&h1s[sl_h1wr + (size_t)w * 4096 + (size_t)b0B * 16 + lane * 4],
               *(const ull_t*)&stg[lane * 4]);
        }
      }
    } else {
      if (s >= 1 && s < 257) {
        if (sub == 0) {
          const f32x4 ez = RGN(7), er = RGN(8), ehx = RGN(9), ehr = RGN(10);
          ushort_t* stg = (ushort_t*)(ldsb + 7168);
#pragma unroll
          for (int r = 0; r < 4; ++r) {
            const float z = sigm(azA[r] + ez[r] + bzs2);
            const float rg = sigm(arrA[r] + er[r] + brs2);
            const float hh = fmaxf(ahxA[r] + ehx[r] + bh20 + rg * (ahrA[r] + ehr[r] + bh21), 0.f);
            const float hn = z * h2st[r] + (1.f - z) * hh;
            h2st[r] = hn;
            stg[(quad * 4 + r) * 16 + l15] = f2bf(hn);
          }
          asm volatile("s_waitcnt lgkmcnt(0)" ::: "memory");
          stc8(&h2s[sl_h2wr + (size_t)w * 4096 + (size_t)b0A * 16 + lane * 4],
               *(const ull_t*)&stg[lane * 4]);
        } else {
          const f32x4 ez = RGN(11), er = RGN(12), ehx = RGN(13), ehr = RGN(14);
          ushort_t* stg = (ushort_t*)(ldsb + 11264);
#pragma unroll
          for (int r = 0; r < 4; ++r) {
            const float z = sigm(azB[r] + ez[r] + bzs2);
            const float rg = sigm(arrB[r] + er[r] + brs2);
            const float hh = fmaxf(ahxB[r] + ehx[r] + bh20 + rg * (ahrB[r] + ehr[r] + bh21), 0.f);
            const float hn = z * h2st[r] + (1.f - z) * hh;
            h2st[r] = hn;
            stg[(quad * 4 + r) * 16 + l15] = f2bf(hn);
          }
          asm volatile("s_waitcnt lgkmcnt(0)" ::: "memory");
          stc8(&h2s[sl_h2wr + (size_t)w * 4096 + (size_t)b0B * 16 + lane * 4],
               *(const ull_t*)&stg[lane * 4]);
        }
      }
    }

    // ---- phase 2 (isC WGs only; WG-uniform barriers) ----
    if (isC) {
      barrier_l();
      if (lay == 0 && s >= 2) {
        if (sub == 1) { RGN(0) = dzA; RGN(1) = drrA; RGN(2) = dhxA; }
        else          { RGN(3) = dzB; RGN(4) = drrB; RGN(5) = dhxB; RGN(6) = dhrB; }
      }
      barrier_l();
      if (lay == 0 && s >= 2) {
        const int t3 = s - 2;
        if (sub == 0) {
          const f32x4 ez = RGN(0), er = RGN(1), ehx = RGN(2);
          ushort_t* stg = (ushort_t*)ldsb;
#pragma unroll
          for (int r = 0; r < 4; ++r) {
            const float z = sigm(dzA[r] + ez[r] + czs);
            const float rg = sigm(drrA[r] + er[r] + crs);
            const float hh = sigm(dhxA[r] + ehx[r] + ch0 + rg * (dhrA[r] + ch1));
            const float hn = z * h3st[r] + (1.f - z) * hh;
            h3st[r] = hn;
            out[((size_t)(b0A + quad * 4 + r) * 256 + t3) * 64 + u3] = hn;
            stg[(quad * 4 + r) * 16 + l15] = f2bf(hn);
          }
          asm volatile("s_waitcnt lgkmcnt(0)" ::: "memory");
          stc8(&h3s[sl_h3wr + (size_t)(w - 28) * 4096 + (size_t)b0A * 16 + lane * 4],
               *(const ull_t*)&stg[lane * 4]);
        } else {
          const f32x4 ez = RGN(3), er = RGN(4), ehx = RGN(5), edhr = RGN(6);
          ushort_t* stg = (ushort_t*)(ldsb + 3072);
#pragma unroll
          for (int r = 0; r < 4; ++r) {
            const float z = sigm(dzB[r] + ez[r] + czs);
            const float rg = sigm(drrB[r] + er[r] + crs);
            const float hh = sigm(dhxB[r] + ehx[r] + ch0 + rg * (edhr[r] + ch1));
            const float hn = z * h3st[r] + (1.f - z) * hh;
            h3st[r] = hn;
            out[((size_t)(b0B + quad * 4 + r) * 256 + t3) * 64 + u3] = hn;
            stg[(quad * 4 + r) * 16 + l15] = f2bf(hn);
          }
          asm volatile("s_waitcnt lgkmcnt(0)" ::: "memory");
          stc8(&h3s[sl_h3wr + (size_t)(w - 28) * 4096 + (size_t)b0B * 16 + lane * 4],
               *(const ull_t*)&stg[lane * 4]);
        }
      }
    }
    __syncthreads();   // drains all global stores (vmcnt 0) + LDS
    if (tid == 0) stc4(&flags[grp * 32 + w], (uint_t)(s + 1));
  }
#undef RGN
}

extern "C" void kernel_launch(void* const* d_in, const int* in_sizes, int n_in,
                              void* d_out, int out_size, void* d_ws, size_t ws_size,
                              hipStream_t stream) {
  const float* x  = (const float*)d_in[0];
  const float* W1 = (const float*)d_in[1];
  const float* R1 = (const float*)d_in[2];
  const float* b1 = (const float*)d_in[3];
  const float* W2 = (const float*)d_in[4];
  const float* R2 = (const float*)d_in[5];
  const float* b2 = (const float*)d_in[6];
  const float* W3 = (const float*)d_in[7];
  const float* R3 = (const float*)d_in[8];
  const float* b3 = (const float*)d_in[9];
  char* ws = (char*)d_ws;
  ushort_t* xbf = (ushort_t*)(ws + OFF_XBF);
  ushort_t* W1t = (ushort_t*)(ws + OFF_W1T);
  ushort_t* R1t = (ushort_t*)(ws + OFF_R1T);
  ushort_t* W2t = (ushort_t*)(ws + OFF_W2T);
  ushort_t* R2t = (ushort_t*)(ws + OFF_R2T);
  ushort_t* W3t = (ushort_t*)(ws + OFF_W3T);
  ushort_t* R3t = (ushort_t*)(ws + OFF_R3T);
  uint_t* cntp  = (uint_t*)(ws + OFF_CNT);

  const bool seq = (ws_size >= SEQ_NEED);
  ushort_t *h1p, *h2p, *h3p;
  if (seq) {
    h1p = (ushort_t*)(ws + OFF_H);
    h2p = (ushort_t*)(ws + OFF_H + H1_BYTES_SEQ);
    h3p = (ushort_t*)(ws + OFF_H + 2UL * H1_BYTES_SEQ);
  } else {
    h1p = (ushort_t*)(ws + OFF_H);
    h2p = (ushort_t*)(ws + OFF_H + H1_BYTES_RING);
    h3p = (ushort_t*)(ws + OFF_H + 2UL * H1_BYTES_RING);
  }

  k_cvtx<<<8192, 256, 0, stream>>>(x, xbf);
  k_tr<<<768, 256, 0, stream>>>(W1, W1t, 128, 1536, 196608);
  k_tr<<<3072, 256, 0, stream>>>(R1, R1t, 512, 1536, 786432);
  k_tr<<<3072, 256, 0, stream>>>(W2, W2t, 512, 1536, 786432);
  k_tr<<<3072, 256, 0, stream>>>(R2, R2t, 512, 1536, 786432);
  k_tr<<<384, 256, 0, stream>>>(W3, W3t, 512, 192, 98304);
  k_tr<<<48, 256, 0, stream>>>(R3, R3t, 64, 192, 12288);
  k_zero<<<546, 256, 0, stream>>>((uint_t*)h1p, (uint_t*)h2p, (uint_t*)h3p, cntp);
  if (seq) {
    gru_main<true><<<256, 256, 0, stream>>>(xbf, W1t, R1t, W2t, R2t, W3t, R3t,
                                            b1, b2, b3, h1p, h2p, h3p, cntp,
                                            (float*)d_out);
  } else {
    gru_main<false><<<256, 256, 0, stream>>>(xbf, W1t, R1t, W2t, R2t, W3t, R3t,
                                             b1, b2, b3, h1p, h2p, h3p, cntp,
                                             (float*)d_out);
  }
}

// Round 10
// 2410.483 us; speedup vs baseline: 1.4938x; 1.4938x over previous
//
#include <hip/hip_runtime.h>

typedef unsigned short ushort_t;
typedef unsigned int uint_t;
typedef unsigned long long ull_t;
typedef __attribute__((ext_vector_type(8))) short short8;
typedef __attribute__((ext_vector_type(4))) float f32x4;

#define MFMA16(a, b, c) __builtin_amdgcn_mfma_f32_16x16x32_bf16((a), (b), (c), 0, 0, 0)

__device__ __forceinline__ ushort_t f2bf(float f) {
  union { float f; uint_t u; } v; v.f = f;
  uint_t r = v.u + 0x7fffu + ((v.u >> 16) & 1u);
  return (ushort_t)(r >> 16);
}
__device__ __forceinline__ float sigm(float x) { return 1.f / (1.f + __expf(-x)); }

// Device-coherent 16B load (two 8B relaxed agent atomics). RING fallback only.
__device__ __forceinline__ short8 ldc(const ushort_t* p) {
  union { ull_t q[2]; short8 v; } u;
  u.q[0] = __hip_atomic_load((const ull_t*)p, __ATOMIC_RELAXED, __HIP_MEMORY_SCOPE_AGENT);
  u.q[1] = __hip_atomic_load((const ull_t*)(p + 4), __ATOMIC_RELAXED, __HIP_MEMORY_SCOPE_AGENT);
  return u.v;
}
template <bool SEQ>
__device__ __forceinline__ short8 ldh(const ushort_t* p) {
  if constexpr (SEQ) return *(const short8*)p;  // fresh (never-reused) address: cached load is coherent
  else return ldc(p);
}
// Write-through stores land at the device coherence point.
__device__ __forceinline__ void stc8(ushort_t* p, ull_t v) {
  __hip_atomic_store((ull_t*)p, v, __ATOMIC_RELAXED, __HIP_MEMORY_SCOPE_AGENT);
}
__device__ __forceinline__ void stc4(uint_t* p, uint_t v) {
  __hip_atomic_store(p, v, __ATOMIC_RELAXED, __HIP_MEMORY_SCOPE_AGENT);
}

// light barrier: drains LDS ops only; global stores stay in flight
__device__ __forceinline__ void barrier_l() {
  asm volatile("s_waitcnt lgkmcnt(0)" ::: "memory");
  __builtin_amdgcn_s_barrier();
  asm volatile("" ::: "memory");
}

__device__ __forceinline__ size_t hidx(int ko, int b0, int l15) {
  return (size_t)((ko >> 4) * 256 + b0 + l15) * 16 + (ko & 15);
}

// ---------------- workspace layout (bytes) ----------------
#define OFF_XBF  0UL            // bf16 x^T [256 t][256 b][128]  16777216
#define OFF_W1T  16777216UL     // bf16 W1^T [1536][128]   393216
#define OFF_R1T  17170432UL     // bf16 R1^T [1536][512]   1572864
#define OFF_W2T  18743296UL     // bf16 W2^T [1536][512]   1572864
#define OFF_R2T  20316160UL     // bf16 R2^T [1536][512]   1572864
#define OFF_W3T  21889024UL     // bf16 W3^T [192][512]    196608
#define OFF_R3T  22085632UL     // bf16 R3^T [192][64]     24576
#define OFF_CNT  22110208UL     // uint flags[8 grp][32 w]
#define OFF_H    22114304UL
#define H1_BYTES_SEQ  (257UL * 262144UL)
#define H3_BYTES_SEQ  (257UL * 32768UL)
#define SEQ_NEED (OFF_H + 2UL * H1_BYTES_SEQ + H3_BYTES_SEQ)
#define H1_BYTES_RING (4UL * 262144UL)

// ---------------- init kernels ----------------
__global__ void k_cvtx(const float* __restrict__ x, ushort_t* __restrict__ xb) {
  const int i = blockIdx.x * 256 + threadIdx.x;
  const int d4 = i & 31;
  const int t = (i >> 5) & 255;
  const int b = i >> 13;
  const float4 v = ((const float4*)x)[i];
  ushort4 o;
  o.x = f2bf(v.x); o.y = f2bf(v.y); o.z = f2bf(v.z); o.w = f2bf(v.w);
  ((ushort4*)xb)[(((t << 8) + b) << 5) + d4] = o;
}

__global__ void k_tr(const float* __restrict__ src, ushort_t* __restrict__ dst,
                     int K, int G, int n) {
  const int i = blockIdx.x * 256 + threadIdx.x;
  if (i >= n) return;
  const int g = i / K, k = i - g * K;
  dst[i] = f2bf(src[(size_t)k * G + g]);
}

__global__ void k_zero(uint_t* h1, uint_t* h2, uint_t* h3, uint_t* cnt) {
  const int i = blockIdx.x * 256 + threadIdx.x;
  if (i < 65536) h1[i] = 0;                    // h1 slot 0 (h1[-1]=0)
  else if (i < 131072) h2[i - 65536] = 0;      // h2 slot 0
  else if (i < 139264) h3[i - 131072] = 0;     // h3 slot 0
  else if (i < 139776) cnt[i - 139264] = 0;
}

// ---------------- persistent pipelined GRU ----------------
// R5 EXACT RESUBMISSION (the verified 2385us kernel). R9's two "safe" deltas
// (isC refill reorder + conditional phase-2 barriers) regressed to 3550us --
// candidate mechanisms: conservative vmcnt(0) at the CFG join between refill
// and B-MFMAs, and barrier-schedule desync turning fast WGs into sustained
// flag-spinners contending with the straggler. This exact-A/B either
// re-establishes 2385 (deltas were harmful) or shows environment variance.
// Structure: W2 in LDS (48KB swizzled, lay1-shared), chain-split epilogues
// (sub0->A, sub1->B), flag-array group barrier (agent loads + __all), all
// staging arrays refilled with chain B via register reuse in single bursts.
template <bool SEQ>
__global__ __launch_bounds__(256, 1)
void gru_main(const ushort_t* __restrict__ xbf,
              const ushort_t* __restrict__ W1t, const ushort_t* __restrict__ R1t,
              const ushort_t* __restrict__ W2t, const ushort_t* __restrict__ R2t,
              const ushort_t* __restrict__ W3t, const ushort_t* __restrict__ R3t,
              const float* __restrict__ b1, const float* __restrict__ b2,
              const float* __restrict__ b3,
              ushort_t* __restrict__ h1s, ushort_t* __restrict__ h2s,
              ushort_t* __restrict__ h3s,
              uint_t* __restrict__ cnt, float* __restrict__ out) {
  __shared__ char ldsb[64512] __attribute__((aligned(16)));
  char* w2b = ldsb + 15360;            // 49152 B swizzled W2
#define RGN(r) (*(f32x4*)(ldsb + ((r) << 10) + ((size_t)lane << 4)))
  const int tid = threadIdx.x, bid = blockIdx.x;
  const int grp = bid & 7;
  const int w = bid >> 3;               // 0..31: u-col group
  const int b0A = grp << 5, b0B = b0A + 16;
  const int lane = tid & 63, wid = tid >> 6;
  const int l15 = lane & 15, quad = lane >> 4, q8 = quad << 3;
  const int lay = wid >> 1, sub = wid & 1;
  const bool isC = (w >= 28);
  const int u = (w << 4) + l15;
  const int u3 = ((w - 28) << 4) + l15;

  // ---- W2 -> LDS (swizzled), by lay1 waves ----
  if (lay == 1) {
#pragma unroll
    for (int g = 0; g < 3; ++g)
#pragma unroll
      for (int kk = 0; kk < 8; ++kk) {
        const int k2 = sub * 8 + kk;
        const short8 v = *(const short8*)&W2t[(size_t)(g * 512 + u) * 512 + k2 * 32 + q8];
        const int off = ((((g * 16 + l15) << 10) + ((k2 * 32 + q8) << 1)) ^ ((l15 & 7) << 4));
        *(short8*)(w2b + off) = v;
      }
  }

  // ---- register-resident weights ----
  short8 wreg[33];
  if (lay == 0) {
    if (sub == 0) {
#pragma unroll
      for (int g = 0; g < 3; ++g) {
#pragma unroll
        for (int kk = 0; kk < 4; ++kk)
          wreg[g * 4 + kk] = *(const short8*)&W1t[(size_t)(g * 512 + u) * 128 + kk * 32 + q8];
#pragma unroll
        for (int kk = 0; kk < 5; ++kk)
          wreg[12 + g * 5 + kk] = *(const short8*)&R1t[(size_t)(g * 512 + u) * 512 + kk * 32 + q8];
      }
    } else {
#pragma unroll
      for (int g = 0; g < 3; ++g)
#pragma unroll
        for (int kk = 0; kk < 11; ++kk)
          wreg[g * 11 + kk] = *(const short8*)&R1t[(size_t)(g * 512 + u) * 512 + (5 + kk) * 32 + q8];
    }
  } else {
#pragma unroll
    for (int g = 0; g < 3; ++g)
#pragma unroll
      for (int kk = 0; kk < 8; ++kk)
        wreg[g * 8 + kk] = *(const short8*)&R2t[(size_t)(g * 512 + u) * 512 + (sub * 8 + kk) * 32 + q8];
  }
  __syncthreads();   // W2 LDS ready

  // ---- biases ----
  const float bzs1 = b1[u] + b1[1536 + u];
  const float brs1 = b1[512 + u] + b1[2048 + u];
  const float bh10 = b1[1024 + u], bh11 = b1[2560 + u];
  const float bzs2 = b2[u] + b2[1536 + u];
  const float brs2 = b2[512 + u] + b2[2048 + u];
  const float bh20 = b2[1024 + u], bh21 = b2[2560 + u];
  float czs = 0, crs = 0, ch0 = 0, ch1 = 0;
  if (isC) {
    czs = b3[u3] + b3[192 + u3];
    crs = b3[64 + u3] + b3[256 + u3];
    ch0 = b3[128 + u3]; ch1 = b3[320 + u3];
  }

  // per-wave persistent state: this wave's epilogue chain
  float h1st[4] = {0, 0, 0, 0};
  float h2st[4] = {0, 0, 0, 0};
  float h3st[4] = {0, 0, 0, 0};
  const f32x4 z4 = {0.f, 0.f, 0.f, 0.f};
  uint_t* flags = cnt;

#pragma unroll 1
  for (int s = 0; s < 258; ++s) {
    // ---- spin: all 32 WGs of the group done with superstep s-1 ----
    {
      const uint_t* fl = flags + grp * 32 + (lane & 31);
      while (true) {
        const uint_t v = __hip_atomic_load(fl, __ATOMIC_RELAXED, __HIP_MEMORY_SCOPE_AGENT);
        if (__all((int)(v >= (uint_t)s))) break;
        __builtin_amdgcn_s_sleep(1);
      }
      asm volatile("" ::: "memory");   // no load hoisting above the spin
    }
    // slot(t) = t+1 (slot 0 = zeros); ush offsets
    const size_t sl_h1rd = (size_t)(SEQ ? s : (s & 3)) * 131072;             // h1[s-1]
    const size_t sl_h1wr = (size_t)(SEQ ? (s + 1) : ((s + 1) & 3)) * 131072;
    const size_t sl_h2rd = (size_t)(SEQ ? (s - 1) : ((s - 1) & 3)) * 131072; // h2[s-2]
    const size_t sl_h2wr = (size_t)(SEQ ? s : (s & 3)) * 131072;             // h2[s-1]
    const size_t sl_h3rd = (size_t)(SEQ ? (s - 2) : ((s - 2) & 3)) * 16384;  // h3[s-3]
    const size_t sl_h3wr = (size_t)(SEQ ? (s - 1) : ((s - 1) & 3)) * 16384;  // h3[s-2]

    f32x4 azA = z4, arrA = z4, ahxA = z4, ahrA = z4;
    f32x4 azB = z4, arrB = z4, ahxB = z4, ahrB = z4;
    f32x4 dzA = z4, drrA = z4, dhxA = z4, dhrA = z4;
    f32x4 dzB = z4, drrB = z4, dhxB = z4, dhrB = z4;

    if (lay == 0) {
      const ushort_t* h1rd = h1s + sl_h1rd;
      const ushort_t* h2rd = h2s + sl_h2rd;
      if (sub == 0) {
        // ------- lay0-sub0: W1 + R1 k[0,160); isC: W3 k[0,256) + R3 -------
        short8 sx[4], sh[5], s2A[8], s3[2];
        // ISSUE burst: chain A (+ L3 A-side)
        if (s < 256) {
          const ushort_t* xrA = xbf + ((size_t)s * 256 + b0A + l15) * 128;
#pragma unroll
          for (int kk = 0; kk < 4; ++kk) sx[kk] = *(const short8*)&xrA[kk * 32 + q8];
#pragma unroll
          for (int kk = 0; kk < 5; ++kk)
            sh[kk] = ldh<SEQ>(&h1rd[hidx(kk * 32 + q8, b0A, l15)]);
        }
        if (isC && s >= 2) {
          const ushort_t* h3rd = h3s + sl_h3rd;
#pragma unroll
          for (int kk = 0; kk < 8; ++kk)
            s2A[kk] = ldh<SEQ>(&h2rd[hidx(kk * 32 + q8, b0A, l15)]);
#pragma unroll
          for (int kk = 0; kk < 2; ++kk)
            s3[kk] = ldh<SEQ>(&h3rd[hidx(kk * 32 + q8, b0A, l15)]);
        }
        if (s < 256) {
          // A MFMAs
#pragma unroll
          for (int kk = 0; kk < 4; ++kk) {
            azA  = MFMA16(sx[kk], wreg[kk], azA);
            arrA = MFMA16(sx[kk], wreg[4 + kk], arrA);
            ahxA = MFMA16(sx[kk], wreg[8 + kk], ahxA);
          }
#pragma unroll
          for (int kk = 0; kk < 5; ++kk) {
            azA  = MFMA16(sh[kk], wreg[12 + kk], azA);
            arrA = MFMA16(sh[kk], wreg[17 + kk], arrA);
            ahrA = MFMA16(sh[kk], wreg[22 + kk], ahrA);
          }
          // refill with chain B (register reuse), one burst
          const ushort_t* xrB = xbf + ((size_t)s * 256 + b0B + l15) * 128;
#pragma unroll
          for (int kk = 0; kk < 4; ++kk) sx[kk] = *(const short8*)&xrB[kk * 32 + q8];
#pragma unroll
          for (int kk = 0; kk < 5; ++kk)
            sh[kk] = ldh<SEQ>(&h1rd[hidx(kk * 32 + q8, b0B, l15)]);
        }
        if (isC && s >= 2) {
          const ushort_t* h3rd = h3s + sl_h3rd;
          // A: h2 @ W3 k[0,256)
#pragma unroll
          for (int kk = 0; kk < 8; ++kk) {
            const int ko = kk * 32 + q8;
            dzA  = MFMA16(s2A[kk], *(const short8*)&W3t[(size_t)u3 * 512 + ko], dzA);
            drrA = MFMA16(s2A[kk], *(const short8*)&W3t[(size_t)(64 + u3) * 512 + ko], drrA);
            dhxA = MFMA16(s2A[kk], *(const short8*)&W3t[(size_t)(128 + u3) * 512 + ko], dhxA);
          }
          // A: h3 @ R3
#pragma unroll
          for (int kk = 0; kk < 2; ++kk) {
            const int ko = kk * 32 + q8;
            dzA  = MFMA16(s3[kk], *(const short8*)&R3t[(size_t)u3 * 64 + ko], dzA);
            drrA = MFMA16(s3[kk], *(const short8*)&R3t[(size_t)(64 + u3) * 64 + ko], drrA);
            dhrA = MFMA16(s3[kk], *(const short8*)&R3t[(size_t)(128 + u3) * 64 + ko], dhrA);
          }
          // refill: B-side h2 + h3 (bursts, register reuse)
#pragma unroll
          for (int kk = 0; kk < 8; ++kk)
            s2A[kk] = ldh<SEQ>(&h2rd[hidx(kk * 32 + q8, b0B, l15)]);
#pragma unroll
          for (int kk = 0; kk < 2; ++kk)
            s3[kk] = ldh<SEQ>(&h3rd[hidx(kk * 32 + q8, b0B, l15)]);
          // B MFMAs
#pragma unroll
          for (int kk = 0; kk < 8; ++kk) {
            const int ko = kk * 32 + q8;
            dzB  = MFMA16(s2A[kk], *(const short8*)&W3t[(size_t)u3 * 512 + ko], dzB);
            drrB = MFMA16(s2A[kk], *(const short8*)&W3t[(size_t)(64 + u3) * 512 + ko], drrB);
            dhxB = MFMA16(s2A[kk], *(const short8*)&W3t[(size_t)(128 + u3) * 512 + ko], dhxB);
          }
#pragma unroll
          for (int kk = 0; kk < 2; ++kk) {
            const int ko = kk * 32 + q8;
            dzB  = MFMA16(s3[kk], *(const short8*)&R3t[(size_t)u3 * 64 + ko], dzB);
            drrB = MFMA16(s3[kk], *(const short8*)&R3t[(size_t)(64 + u3) * 64 + ko], drrB);
            dhrB = MFMA16(s3[kk], *(const short8*)&R3t[(size_t)(128 + u3) * 64 + ko], dhrB);
          }
        }
        if (s < 256) {
          // B MFMAs
#pragma unroll
          for (int kk = 0; kk < 4; ++kk) {
            azB  = MFMA16(sx[kk], wreg[kk], azB);
            arrB = MFMA16(sx[kk], wreg[4 + kk], arrB);
            ahxB = MFMA16(sx[kk], wreg[8 + kk], ahxB);
          }
#pragma unroll
          for (int kk = 0; kk < 5; ++kk) {
            azB  = MFMA16(sh[kk], wreg[12 + kk], azB);
            arrB = MFMA16(sh[kk], wreg[17 + kk], arrB);
            ahrB = MFMA16(sh[kk], wreg[22 + kk], ahrB);
          }
        }
      } else {
        // ------- lay0-sub1: R1 k[160,512); isC: W3 k[256,512) -------
        short8 sh[11], s2A[8];
        if (s < 256) {
#pragma unroll
          for (int kk = 0; kk < 11; ++kk)
            sh[kk] = ldh<SEQ>(&h1rd[hidx((5 + kk) * 32 + q8, b0A, l15)]);
        }
        if (isC && s >= 2) {
#pragma unroll
          for (int kk = 0; kk < 8; ++kk)
            s2A[kk] = ldh<SEQ>(&h2rd[hidx((8 + kk) * 32 + q8, b0A, l15)]);
        }
        if (s < 256) {
#pragma unroll
          for (int kk = 0; kk < 11; ++kk) {
            azA  = MFMA16(sh[kk], wreg[kk], azA);
            arrA = MFMA16(sh[kk], wreg[11 + kk], arrA);
            ahrA = MFMA16(sh[kk], wreg[22 + kk], ahrA);
          }
          // refill with chain B (one burst)
#pragma unroll
          for (int kk = 0; kk < 11; ++kk)
            sh[kk] = ldh<SEQ>(&h1rd[hidx((5 + kk) * 32 + q8, b0B, l15)]);
#pragma unroll
          for (int kk = 0; kk < 11; ++kk) {
            azB  = MFMA16(sh[kk], wreg[kk], azB);
            arrB = MFMA16(sh[kk], wreg[11 + kk], arrB);
            ahrB = MFMA16(sh[kk], wreg[22 + kk], ahrB);
          }
        }
        if (isC && s >= 2) {
#pragma unroll
          for (int kk = 0; kk < 8; ++kk) {
            const int ko = (8 + kk) * 32 + q8;
            dzA  = MFMA16(s2A[kk], *(const short8*)&W3t[(size_t)u3 * 512 + ko], dzA);
            drrA = MFMA16(s2A[kk], *(const short8*)&W3t[(size_t)(64 + u3) * 512 + ko], drrA);
            dhxA = MFMA16(s2A[kk], *(const short8*)&W3t[(size_t)(128 + u3) * 512 + ko], dhxA);
          }
          // refill B-side h2 (one burst)
#pragma unroll
          for (int kk = 0; kk < 8; ++kk)
            s2A[kk] = ldh<SEQ>(&h2rd[hidx((8 + kk) * 32 + q8, b0B, l15)]);
#pragma unroll
          for (int kk = 0; kk < 8; ++kk) {
            const int ko = (8 + kk) * 32 + q8;
            dzB  = MFMA16(s2A[kk], *(const short8*)&W3t[(size_t)u3 * 512 + ko], dzB);
            drrB = MFMA16(s2A[kk], *(const short8*)&W3t[(size_t)(64 + u3) * 512 + ko], drrB);
            dhxB = MFMA16(s2A[kk], *(const short8*)&W3t[(size_t)(128 + u3) * 512 + ko], dhxB);
          }
        }
      }
    } else {
      // ------- lay1: W2 (LDS) + R2 (regs), K-half [sub*256, sub*256+256) -------
      if (s >= 1 && s < 257) {
        const ushort_t* h1rd = h1s + sl_h1rd;
        const ushort_t* h2rd = h2s + sl_h2rd;
        short8 sa[8], sb[8];
#pragma unroll
        for (int kk = 0; kk < 8; ++kk) {
          const size_t ao = hidx((sub * 8 + kk) * 32 + q8, b0A, l15);
          sa[kk] = ldh<SEQ>(&h1rd[ao]);
          sb[kk] = ldh<SEQ>(&h2rd[ao]);
        }
#pragma unroll
        for (int kk = 0; kk < 8; ++kk) {
          const int ko = (sub * 8 + kk) * 32 + q8;
          const int o0 = ((((0 * 16 + l15) << 10) + (ko << 1)) ^ ((l15 & 7) << 4));
          const int o1 = ((((1 * 16 + l15) << 10) + (ko << 1)) ^ ((l15 & 7) << 4));
          const int o2 = ((((2 * 16 + l15) << 10) + (ko << 1)) ^ ((l15 & 7) << 4));
          azA  = MFMA16(sa[kk], *(const short8*)(w2b + o0), azA);
          arrA = MFMA16(sa[kk], *(const short8*)(w2b + o1), arrA);
          ahxA = MFMA16(sa[kk], *(const short8*)(w2b + o2), ahxA);
          azA  = MFMA16(sb[kk], wreg[kk], azA);
          arrA = MFMA16(sb[kk], wreg[8 + kk], arrA);
          ahrA = MFMA16(sb[kk], wreg[16 + kk], ahrA);
        }
        // refill with chain B (register reuse)
#pragma unroll
        for (int kk = 0; kk < 8; ++kk) {
          const size_t ao = hidx((sub * 8 + kk) * 32 + q8, b0B, l15);
          sa[kk] = ldh<SEQ>(&h1rd[ao]);
          sb[kk] = ldh<SEQ>(&h2rd[ao]);
        }
#pragma unroll
        for (int kk = 0; kk < 8; ++kk) {
          const int ko = (sub * 8 + kk) * 32 + q8;
          const int o0 = ((((0 * 16 + l15) << 10) + (ko << 1)) ^ ((l15 & 7) << 4));
          const int o1 = ((((1 * 16 + l15) << 10) + (ko << 1)) ^ ((l15 & 7) << 4));
          const int o2 = ((((2 * 16 + l15) << 10) + (ko << 1)) ^ ((l15 & 7) << 4));
          azB  = MFMA16(sa[kk], *(const short8*)(w2b + o0), azB);
          arrB = MFMA16(sa[kk], *(const short8*)(w2b + o1), arrB);
          ahxB = MFMA16(sa[kk], *(const short8*)(w2b + o2), ahxB);
          azB  = MFMA16(sb[kk], wreg[kk], azB);
          arrB = MFMA16(sb[kk], wreg[8 + kk], arrB);
          ahrB = MFMA16(sb[kk], wreg[16 + kk], ahrB);
        }
      }
    }

    // ---- phase 1: partner-chain partial writes ----
    if (lay == 0) {
      if (sub == 1) {
        if (s < 256) { RGN(0) = azA; RGN(1) = arrA; RGN(2) = ahrA; }
      } else {
        if (s < 256) { RGN(3) = azB; RGN(4) = arrB; RGN(5) = ahxB; RGN(6) = ahrB; }
      }
    } else {
      if (s >= 1 && s < 257) {
        if (sub == 1) { RGN(7) = azA; RGN(8) = arrA; RGN(9) = ahxA; RGN(10) = ahrA; }
        else          { RGN(11) = azB; RGN(12) = arrB; RGN(13) = ahxB; RGN(14) = ahrB; }
      }
    }
    barrier_l();

    // ---- L1/L2 epilogues (sub0 -> chain A, sub1 -> chain B) ----
    if (lay == 0) {
      if (sub == 0) {
        if (s < 256) {
          const f32x4 ez = RGN(0), er = RGN(1), ehr = RGN(2);
          ushort_t* stg = (ushort_t*)ldsb;
#pragma unroll
          for (int r = 0; r < 4; ++r) {
            const float z = sigm(azA[r] + ez[r] + bzs1);
            const float rg = sigm(arrA[r] + er[r] + brs1);
            const float hh = fmaxf(ahxA[r] + bh10 + rg * (ahrA[r] + ehr[r] + bh11), 0.f);
            const float hn = z * h1st[r] + (1.f - z) * hh;
            h1st[r] = hn;
            stg[(quad * 4 + r) * 16 + l15] = f2bf(hn);
          }
          asm volatile("s_waitcnt lgkmcnt(0)" ::: "memory");
          stc8(&h1s[sl_h1wr + (size_t)w * 4096 + (size_t)b0A * 16 + lane * 4],
               *(const ull_t*)&stg[lane * 4]);
        }
      } else {
        if (s < 256) {
          const f32x4 ez = RGN(3), er = RGN(4), ehx = RGN(5), ehr = RGN(6);
          ushort_t* stg = (ushort_t*)(ldsb + 3072);
#pragma unroll
          for (int r = 0; r < 4; ++r) {
            const float z = sigm(azB[r] + ez[r] + bzs1);
            const float rg = sigm(arrB[r] + er[r] + brs1);
            const float hh = fmaxf(ehx[r] + bh10 + rg * (ahrB[r] + ehr[r] + bh11), 0.f);
            const float hn = z * h1st[r] + (1.f - z) * hh;
            h1st[r] = hn;
            stg[(quad * 4 + r) * 16 + l15] = f2bf(hn);
          }
          asm volatile("s_waitcnt lgkmcnt(0)" ::: "memory");
          stc8(&h1s[sl_h1wr + (size_t)w * 4096 + (size_t)b0B * 16 + lane * 4],
               *(const ull_t*)&stg[lane * 4]);
        }
      }
    } else {
      if (s >= 1 && s < 257) {
        if (sub == 0) {
          const f32x4 ez = RGN(7), er = RGN(8), ehx = RGN(9), ehr = RGN(10);
          ushort_t* stg = (ushort_t*)(ldsb + 7168);
#pragma unroll
          for (int r = 0; r < 4; ++r) {
            const float z = sigm(azA[r] + ez[r] + bzs2);
            const float rg = sigm(arrA[r] + er[r] + brs2);
            const float hh = fmaxf(ahxA[r] + ehx[r] + bh20 + rg * (ahrA[r] + ehr[r] + bh21), 0.f);
            const float hn = z * h2st[r] + (1.f - z) * hh;
            h2st[r] = hn;
            stg[(quad * 4 + r) * 16 + l15] = f2bf(hn);
          }
          asm volatile("s_waitcnt lgkmcnt(0)" ::: "memory");
          stc8(&h2s[sl_h2wr + (size_t)w * 4096 + (size_t)b0A * 16 + lane * 4],
               *(const ull_t*)&stg[lane * 4]);
        } else {
          const f32x4 ez = RGN(11), er = RGN(12), ehx = RGN(13), ehr = RGN(14);
          ushort_t* stg = (ushort_t*)(ldsb + 11264);
#pragma unroll
          for (int r = 0; r < 4; ++r) {
            const float z = sigm(azB[r] + ez[r] + bzs2);
            const float rg = sigm(arrB[r] + er[r] + brs2);
            const float hh = fmaxf(ahxB[r] + ehx[r] + bh20 + rg * (ahrB[r] + ehr[r] + bh21), 0.f);
            const float hn = z * h2st[r] + (1.f - z) * hh;
            h2st[r] = hn;
            stg[(quad * 4 + r) * 16 + l15] = f2bf(hn);
          }
          asm volatile("s_waitcnt lgkmcnt(0)" ::: "memory");
          stc8(&h2s[sl_h2wr + (size_t)w * 4096 + (size_t)b0B * 16 + lane * 4],
               *(const ull_t*)&stg[lane * 4]);
        }
      }
    }
    barrier_l();

    // ---- phase 2: L3 exchange (reuses regions 0-6) ----
    if (isC && lay == 0 && s >= 2) {
      if (sub == 1) { RGN(0) = dzA; RGN(1) = drrA; RGN(2) = dhxA; }
      else          { RGN(3) = dzB; RGN(4) = drrB; RGN(5) = dhxB; RGN(6) = dhrB; }
    }
    barrier_l();
    if (isC && lay == 0 && s >= 2) {
      const int t3 = s - 2;
      if (sub == 0) {
        const f32x4 ez = RGN(0), er = RGN(1), ehx = RGN(2);
        ushort_t* stg = (ushort_t*)ldsb;
#pragma unroll
        for (int r = 0; r < 4; ++r) {
          const float z = sigm(dzA[r] + ez[r] + czs);
          const float rg = sigm(drrA[r] + er[r] + crs);
          const float hh = sigm(dhxA[r] + ehx[r] + ch0 + rg * (dhrA[r] + ch1));
          const float hn = z * h3st[r] + (1.f - z) * hh;
          h3st[r] = hn;
          out[((size_t)(b0A + quad * 4 + r) * 256 + t3) * 64 + u3] = hn;
          stg[(quad * 4 + r) * 16 + l15] = f2bf(hn);
        }
        asm volatile("s_waitcnt lgkmcnt(0)" ::: "memory");
        stc8(&h3s[sl_h3wr + (size_t)(w - 28) * 4096 + (size_t)b0A * 16 + lane * 4],
             *(const ull_t*)&stg[lane * 4]);
      } else {
        const f32x4 ez = RGN(3), er = RGN(4), ehx = RGN(5), edhr = RGN(6);
        ushort_t* stg = (ushort_t*)(ldsb + 3072);
#pragma unroll
        for (int r = 0; r < 4; ++r) {
          const float z = sigm(dzB[r] + ez[r] + czs);
          const float rg = sigm(drrB[r] + er[r] + crs);
          const float hh = sigm(dhxB[r] + ehx[r] + ch0 + rg * (edhr[r] + ch1));
          const float hn = z * h3st[r] + (1.f - z) * hh;
          h3st[r] = hn;
          out[((size_t)(b0B + quad * 4 + r) * 256 + t3) * 64 + u3] = hn;
          stg[(quad * 4 + r) * 16 + l15] = f2bf(hn);
        }
        asm volatile("s_waitcnt lgkmcnt(0)" ::: "memory");
        stc8(&h3s[sl_h3wr + (size_t)(w - 28) * 4096 + (size_t)b0B * 16 + lane * 4],
             *(const ull_t*)&stg[lane * 4]);
      }
    }
    __syncthreads();   // drains all global stores (vmcnt 0) + LDS
    if (tid == 0) stc4(&flags[grp * 32 + w], (uint_t)(s + 1));
  }
#undef RGN
}

extern "C" void kernel_launch(void* const* d_in, const int* in_sizes, int n_in,
                              void* d_out, int out_size, void* d_ws, size_t ws_size,
                              hipStream_t stream) {
  const float* x  = (const float*)d_in[0];
  const float* W1 = (const float*)d_in[1];
  const float* R1 = (const float*)d_in[2];
  const float* b1 = (const float*)d_in[3];
  const float* W2 = (const float*)d_in[4];
  const float* R2 = (const float*)d_in[5];
  const float* b2 = (const float*)d_in[6];
  const float* W3 = (const float*)d_in[7];
  const float* R3 = (const float*)d_in[8];
  const float* b3 = (const float*)d_in[9];
  char* ws = (char*)d_ws;
  ushort_t* xbf = (ushort_t*)(ws + OFF_XBF);
  ushort_t* W1t = (ushort_t*)(ws + OFF_W1T);
  ushort_t* R1t = (ushort_t*)(ws + OFF_R1T);
  ushort_t* W2t = (ushort_t*)(ws + OFF_W2T);
  ushort_t* R2t = (ushort_t*)(ws + OFF_R2T);
  ushort_t* W3t = (ushort_t*)(ws + OFF_W3T);
  ushort_t* R3t = (ushort_t*)(ws + OFF_R3T);
  uint_t* cntp  = (uint_t*)(ws + OFF_CNT);

  const bool seq = (ws_size >= SEQ_NEED);
  ushort_t *h1p, *h2p, *h3p;
  if (seq) {
    h1p = (ushort_t*)(ws + OFF_H);
    h2p = (ushort_t*)(ws + OFF_H + H1_BYTES_SEQ);
    h3p = (ushort_t*)(ws + OFF_H + 2UL * H1_BYTES_SEQ);
  } else {
    h1p = (ushort_t*)(ws + OFF_H);
    h2p = (ushort_t*)(ws + OFF_H + H1_BYTES_RING);
    h3p = (ushort_t*)(ws + OFF_H + 2UL * H1_BYTES_RING);
  }

  k_cvtx<<<8192, 256, 0, stream>>>(x, xbf);
  k_tr<<<768, 256, 0, stream>>>(W1, W1t, 128, 1536, 196608);
  k_tr<<<3072, 256, 0, stream>>>(R1, R1t, 512, 1536, 786432);
  k_tr<<<3072, 256, 0, stream>>>(W2, W2t, 512, 1536, 786432);
  k_tr<<<3072, 256, 0, stream>>>(R2, R2t, 512, 1536, 786432);
  k_tr<<<384, 256, 0, stream>>>(W3, W3t, 512, 192, 98304);
  k_tr<<<48, 256, 0, stream>>>(R3, R3t, 64, 192, 12288);
  k_zero<<<546, 256, 0, stream>>>((uint_t*)h1p, (uint_t*)h2p, (uint_t*)h3p, cntp);
  if (seq) {
    gru_main<true><<<256, 256, 0, stream>>>(xbf, W1t, R1t, W2t, R2t, W3t, R3t,
                                            b1, b2, b3, h1p, h2p, h3p, cntp,
                                            (float*)d_out);
  } else {
    gru_main<false><<<256, 256, 0, stream>>>(xbf, W1t, R1t, W2t, R2t, W3t, R3t,
                                             b1, b2, b3, h1p, h2p, h3p, cntp,
                                             (float*)d_out);
  }
}